// Round 8
// baseline (426.498 us; speedup 1.0000x reference)
//
#include <hip/hip_runtime.h>
#include <hip/hip_cooperative_groups.h>
#include <hip/hip_fp16.h>
#include <math.h>

namespace cg = cooperative_groups;

// ---------------------------------------------------------------------------
// GAT 2-layer forward. N=50000, E=1.6M (+N self loops), F: 128 -> (4x32) -> 64.
// R2: CSR via two-pass bucket sort of packed (dst<<16|src) codes.
// R4: fp16-MFMA GEMMs with fused attention-dot epilogue; fp16 inter-stage.
// R5: LDS (exp,offset) exchange in aggregates.
// R7: 6 dispatches, ~65us of launch gaps measured between them.
// R8: ONE cooperative mega-kernel. 256 blocks x 1024 thr (16 waves/CU,
// VGPR<=128 via launch_bounds, LDS union 33.3KB -> 1 block/CU co-resident).
// Phases split by grid.sync(): zero | splitA||gemm1 | passB | agg1 | gemm2
// | agg2. Same math as R7 -> same absmax.
// ---------------------------------------------------------------------------

#define NB_BUCKETS 256   // max coarse buckets (dst>>8); used = ceil(N/256)
#define BCAP 16384       // capacity per coarse bucket region (avg ~8448)

typedef _Float16 half8 __attribute__((ext_vector_type(8)));
typedef float    floatx4 __attribute__((ext_vector_type(4)));

struct f2 { float x, y; };   // POD pair (HIP float2 has ctors; unions dislike)

__device__ __forceinline__ unsigned short f2h_bits(float f) {
    return __half_as_ushort(__float2half(f));
}
__device__ __forceinline__ float h2f_lo(unsigned int u) {
    return __half2float(__ushort_as_half((unsigned short)(u & 0xFFFFu)));
}
__device__ __forceinline__ float h2f_hi(unsigned int u) {
    return __half2float(__ushort_as_half((unsigned short)(u >> 16)));
}

// Shared-memory arena: max(Bs 32KB, exs 16*4*65*8=33.28KB, passB 4KB, splitA 3KB)
#define SM_BYTES 33280

// ---------------------------------------------------------------------------
// splitA body (1024 thr): block-aggregated split into coarse buckets by dst>>8
// ---------------------------------------------------------------------------
__device__ void splitA_body(char* sm, int vb, const int* __restrict__ eidx,
        unsigned int* __restrict__ tmp, int* __restrict__ coarse_fill,
        int E, int etot, int nb)
{
    int* hist = (int*)sm;
    int* gb   = hist + 256;
    int* cnt2 = gb + 256;
    int t = threadIdx.x;
    if (t < 256) { hist[t] = 0; cnt2[t] = 0; }
    __syncthreads();

    unsigned int val[4];
    int bkt[4];
    int base = vb * 4096;
    #pragma unroll
    for (int i = 0; i < 4; i++) {
        int idx = base + i * 1024 + t;
        if (idx < etot) {
            unsigned int s, d;
            if (idx < E) { s = (unsigned int)eidx[idx]; d = (unsigned int)eidx[E + idx]; }
            else         { s = (unsigned int)(idx - E); d = s; }
            val[i] = (d << 16) | s;
            bkt[i] = (int)(d >> 8);
            atomicAdd(&hist[bkt[i]], 1);
        } else {
            bkt[i] = -1;
        }
    }
    __syncthreads();
    if (t < nb) {
        int n = hist[t];
        gb[t] = (n > 0) ? atomicAdd(&coarse_fill[t], n) : 0;
    }
    __syncthreads();
    #pragma unroll
    for (int i = 0; i < 4; i++) {
        if (bkt[i] >= 0) {
            int loc = atomicAdd(&cnt2[bkt[i]], 1);
            tmp[(size_t)bkt[i] * BCAP + gb[bkt[i]] + loc] = val[i];
        }
    }
}

// ---------------------------------------------------------------------------
// GEMM (fp16 MFMA) + attention dots + fp16 payload (1024 thr: 256 rows/block,
// one W staging serves 16 waves x 16 rows).
// ---------------------------------------------------------------------------
template<int NT, int H, bool AF16>
__device__ void gemm_body(char* sm, int vb,
        const void* __restrict__ Xv, const float* __restrict__ W,
        const float* __restrict__ att_s, const float* __restrict__ att_d,
        unsigned short* __restrict__ Hf16, float* __restrict__ as_,
        float* __restrict__ ad_, int M)
{
    constexpr int D = NT * 16;      // output width
    constexpr int C = D / H;        // channels per head
    _Float16* Bs = (_Float16*)sm;

    int t = threadIdx.x;
    for (int idx = t; idx < 128 * D; idx += 1024) {
        int k = idx / D;
        int n = idx - k * D;
        int nt = n >> 4, ks = k >> 5;
        int lane = (((k >> 3) & 3) << 4) | (n & 15);
        int j = k & 7;
        Bs[(((nt * 4 + ks) * 64 + lane) << 3) + j] = (_Float16)W[idx];
    }
    __syncthreads();

    int lane = t & 63;
    int wave = t >> 6;
    int quad = lane >> 4, colL = lane & 15;
    int row0 = vb * 256 + wave * 16;

    int arow = row0 + colL; if (arow > M - 1) arow = M - 1;
    half8 afrag[4];
    if constexpr (AF16) {
        const unsigned short* Xh = (const unsigned short*)Xv;
        #pragma unroll
        for (int ks = 0; ks < 4; ks++)
            afrag[ks] = *(const half8*)(const void*)(Xh + (size_t)arow * 128 + ks * 32 + quad * 8);
    } else {
        const float* Xf = (const float*)Xv;
        #pragma unroll
        for (int ks = 0; ks < 4; ks++) {
            const float* pa = Xf + (size_t)arow * 128 + ks * 32 + quad * 8;
            float4 a0 = *(const float4*)pa;
            float4 a1 = *(const float4*)(pa + 4);
            half8 f;
            f[0] = (_Float16)a0.x; f[1] = (_Float16)a0.y;
            f[2] = (_Float16)a0.z; f[3] = (_Float16)a0.w;
            f[4] = (_Float16)a1.x; f[5] = (_Float16)a1.y;
            f[6] = (_Float16)a1.z; f[7] = (_Float16)a1.w;
            afrag[ks] = f;
        }
    }

    floatx4 acc[NT];
    #pragma unroll
    for (int nt = 0; nt < NT; nt++) {
        floatx4 c = {0.f, 0.f, 0.f, 0.f};
        #pragma unroll
        for (int ks = 0; ks < 4; ks++) {
            half8 b = *(half8*)(void*)&Bs[(((nt * 4 + ks) * 64 + lane) << 3)];
            c = __builtin_amdgcn_mfma_f32_16x16x32_f16(afrag[ks], b, c, 0, 0, 0);
        }
        acc[nt] = c;
    }

    float atts[NT], attd[NT];
    #pragma unroll
    for (int nt = 0; nt < NT; nt++) {
        int ch = nt * 16 + colL;
        atts[nt] = att_s[ch];
        attd[nt] = att_d[ch];
    }
    float ps[H][4], pd[H][4];
    #pragma unroll
    for (int h = 0; h < H; h++)
        #pragma unroll
        for (int r = 0; r < 4; r++) { ps[h][r] = 0.f; pd[h][r] = 0.f; }
    #pragma unroll
    for (int nt = 0; nt < NT; nt++) {
        int h = (nt * 16) / C;
        #pragma unroll
        for (int r = 0; r < 4; r++) {
            ps[h][r] += acc[nt][r] * atts[nt];
            pd[h][r] += acc[nt][r] * attd[nt];
        }
    }
    #pragma unroll
    for (int h = 0; h < H; h++)
        #pragma unroll
        for (int r = 0; r < 4; r++)
            #pragma unroll
            for (int off = 1; off < 16; off <<= 1) {
                ps[h][r] += __shfl_xor(ps[h][r], off);
                pd[h][r] += __shfl_xor(pd[h][r], off);
            }
    if (colL < H) {
        #pragma unroll
        for (int r = 0; r < 4; r++) {
            int row = row0 + quad * 4 + r;
            if (row < M) {
                float vs, vd;
                if constexpr (H == 4) {
                    vs = colL == 0 ? ps[0][r] : colL == 1 ? ps[1][r] : colL == 2 ? ps[2][r] : ps[3][r];
                    vd = colL == 0 ? pd[0][r] : colL == 1 ? pd[1][r] : colL == 2 ? pd[2][r] : pd[3][r];
                } else {
                    vs = ps[0][r]; vd = pd[0][r];
                }
                as_[(size_t)row * H + colL] = vs;
                ad_[(size_t)row * H + colL] = vd;
            }
        }
    }

    #pragma unroll
    for (int r = 0; r < 4; r++) {
        int row = row0 + quad * 4 + r;
        if (row < M) {
            #pragma unroll
            for (int nt = 0; nt < NT; nt++)
                Hf16[(size_t)row * D + nt * 16 + colL] = f2h_bits(acc[nt][r]);
        }
    }
}

// ---------------------------------------------------------------------------
// passB body (1024 thr): inline scan + per-bucket counting sort -> col + rowp
// ---------------------------------------------------------------------------
__device__ void passB_body(char* sm, int b, const unsigned int* __restrict__ tmp,
        const int* __restrict__ cfill, int* __restrict__ col,
        int* __restrict__ rowp, int N_, int nb, int etot)
{
    int* sd    = (int*)sm;
    int* hist2 = sd + 256;
    int* scn   = hist2 + 256;
    int* off2  = scn + 256;
    int t = threadIdx.x;

    if (t < 256) sd[t] = (t < nb) ? cfill[t] : 0;
    __syncthreads();
    for (int off = 1; off < 256; off <<= 1) {
        int y = 0;
        if (t < 256 && t >= off) y = sd[t - off];
        __syncthreads();
        if (t < 256) sd[t] += y;
        __syncthreads();
    }
    int base = sd[b] - cfill[b];     // exclusive prefix for this bucket
    int n = cfill[b];
    const unsigned int* seg = tmp + (size_t)b * BCAP;

    if (t < 256) hist2[t] = 0;
    __syncthreads();
    for (int i = t; i < n; i += 1024) {
        unsigned int v = seg[i];
        atomicAdd(&hist2[(v >> 16) & 255], 1);
    }
    __syncthreads();
    int myc = (t < 256) ? hist2[t] : 0;
    if (t < 256) scn[t] = myc;
    __syncthreads();
    for (int off = 1; off < 256; off <<= 1) {
        int y = 0;
        if (t < 256 && t >= off) y = scn[t - off];
        __syncthreads();
        if (t < 256) scn[t] += y;
        __syncthreads();
    }
    if (t < 256) {
        int excl = scn[t] - myc;
        off2[t] = excl;
        int node = b * 256 + t;
        if (node <= N_) rowp[node] = base + excl;
        if (node == N_) rowp[N_] = etot;
    }
    __syncthreads();
    for (int i = t; i < n; i += 1024) {
        unsigned int v = seg[i];
        int bin = (v >> 16) & 255;
        int loc = atomicAdd(&off2[bin], 1);
        col[base + loc] = (int)(v & 0xFFFFu);
    }
}

// ---------------------------------------------------------------------------
// Fused online-softmax segment aggregate; one wave per dst node (16/block).
// No block-level barriers inside -> waves drift freely across virtual blocks.
// ---------------------------------------------------------------------------
template<int H, int C, bool ELU_, bool OUTF16>
__device__ void agg_body(char* sm, int vb,
        const int* __restrict__ row_ptr, const int* __restrict__ col_src,
        const unsigned short* __restrict__ payload, const float* __restrict__ asv,
        const float* __restrict__ adv, const float* __restrict__ bias,
        void* __restrict__ outv, int nnodes)
{
    constexpr int D = H * C;
    constexpr int CPL = 8;            // channels per lane (uint4 of halves)
    constexpr int LPE = D / CPL;      // lanes per edge: 16 (L1) or 8 (L2)
    constexpr int EPI = 64 / LPE;     // edges per inner iter: 4 or 8
    f2* exs = (f2*)sm;                // [16 waves][H][65]
    int wave = threadIdx.x >> 6, lane = threadIdx.x & 63;
    int node = vb * 16 + wave;
    if (node >= nnodes) return;
    int start = row_ptr[node];
    int deg   = row_ptr[node + 1] - start;   // >= 1 (self loop)
    int li  = lane & (LPE - 1);
    int sub = lane / LPE;
    int myh = (li * CPL) / C;
    int lane_off = li * 16;                  // byte offset within a row
    f2* exw = exs + (size_t)wave * H * 65;

    float adh[H];
    #pragma unroll
    for (int h = 0; h < H; h++) adh[h] = adv[(size_t)node * H + h];

    float m[H];
    #pragma unroll
    for (int h = 0; h < H; h++) m[h] = -3.0e38f;
    float acc[CPL];
    #pragma unroll
    for (int k = 0; k < CPL; k++) acc[k] = 0.f;
    float sacc = 0.f;
    const char* pb = (const char*)payload;

    for (int c0 = 0; c0 < deg; c0 += 64) {
        int cnt = deg - c0; if (cnt > 64) cnt = 64;
        int idx = c0 + lane;
        int svec = 0;
        float e[H];
        if (idx < deg) {
            svec = col_src[start + idx];
            if constexpr (H == 4) {
                float4 av = *(const float4*)(asv + (size_t)svec * 4);
                float t0 = av.x + adh[0], t1 = av.y + adh[1];
                float t2 = av.z + adh[2], t3 = av.w + adh[3];
                e[0] = fmaxf(t0, 0.2f * t0); e[1] = fmaxf(t1, 0.2f * t1);
                e[2] = fmaxf(t2, 0.2f * t2); e[3] = fmaxf(t3, 0.2f * t3);
            } else {
                float tt = asv[svec] + adh[0];
                e[0] = fmaxf(tt, 0.2f * tt);
            }
        } else {
            #pragma unroll
            for (int h = 0; h < H; h++) e[h] = -3.0e38f;
        }
        // chunk max per head -> running max update + rescale
        float nm[H];
        #pragma unroll
        for (int h = 0; h < H; h++) {
            float v = e[h];
            #pragma unroll
            for (int off = 32; off >= 1; off >>= 1)
                v = fmaxf(v, __shfl_xor(v, off));
            nm[h] = fmaxf(m[h], v);
        }
        float sc = __expf(m[myh] - nm[myh]);  // first chunk: 0
        sacc *= sc;
        #pragma unroll
        for (int k = 0; k < CPL; k++) acc[k] *= sc;
        #pragma unroll
        for (int h = 0; h < H; h++) m[h] = nm[h];

        // producer: write {exp, row byte-offset} per head into wave-local LDS
        unsigned int boff = (unsigned int)svec * (unsigned int)(D * 2);
        float boff_f = __uint_as_float(boff);
        #pragma unroll
        for (int h = 0; h < H; h++) {
            float ex = (idx < deg) ? __expf(e[h] - m[h]) : 0.f;
            exw[h * 65 + lane].x = ex;
            exw[h * 65 + lane].y = boff_f;
        }

        // consumer: EPI edges per iteration, no cross-lane ops, no masking
        int iters = (cnt + EPI - 1) / EPI;
        #pragma unroll 2
        for (int it = 0; it < iters; it++) {
            int el = it * EPI + sub;
            f2 v = exw[myh * 65 + el];
            float exj = v.x;
            unsigned int off = __float_as_uint(v.y);
            uint4 hv = *(const uint4*)(const void*)(pb + off + lane_off);
            sacc += exj;
            acc[0] = fmaf(h2f_lo(hv.x), exj, acc[0]);
            acc[1] = fmaf(h2f_hi(hv.x), exj, acc[1]);
            acc[2] = fmaf(h2f_lo(hv.y), exj, acc[2]);
            acc[3] = fmaf(h2f_hi(hv.y), exj, acc[3]);
            acc[4] = fmaf(h2f_lo(hv.z), exj, acc[4]);
            acc[5] = fmaf(h2f_hi(hv.z), exj, acc[5]);
            acc[6] = fmaf(h2f_lo(hv.w), exj, acc[6]);
            acc[7] = fmaf(h2f_hi(hv.w), exj, acc[7]);
        }
    }

    #pragma unroll
    for (int off = LPE; off < 64; off <<= 1) {
        sacc += __shfl_xor(sacc, off);
        #pragma unroll
        for (int k = 0; k < CPL; k++) acc[k] += __shfl_xor(acc[k], off);
    }
    if (sub == 0) {
        float inv = 1.f / (sacc + 1e-16f);
        int ch = li * CPL;
        float r[CPL];
        #pragma unroll
        for (int k = 0; k < CPL; k++) {
            r[k] = acc[k] * inv + bias[ch + k];
            if (ELU_) r[k] = r[k] > 0.f ? r[k] : (__expf(r[k]) - 1.f);
        }
        if constexpr (OUTF16) {
            unsigned short* o = (unsigned short*)outv;
            unsigned int w0 = (unsigned int)f2h_bits(r[0]) | ((unsigned int)f2h_bits(r[1]) << 16);
            unsigned int w1 = (unsigned int)f2h_bits(r[2]) | ((unsigned int)f2h_bits(r[3]) << 16);
            unsigned int w2 = (unsigned int)f2h_bits(r[4]) | ((unsigned int)f2h_bits(r[5]) << 16);
            unsigned int w3 = (unsigned int)f2h_bits(r[6]) | ((unsigned int)f2h_bits(r[7]) << 16);
            uint4 q = { w0, w1, w2, w3 };
            *(uint4*)(void*)(o + (size_t)node * D + ch) = q;
        } else {
            float* o = (float*)outv;
            float4 w0 = { r[0], r[1], r[2], r[3] };
            float4 w1 = { r[4], r[5], r[6], r[7] };
            *(float4*)(o + (size_t)node * D + ch) = w0;
            *(float4*)(o + (size_t)node * D + ch + 4) = w1;
        }
    }
}

// ---------------------------------------------------------------------------
// Cooperative mega-kernel: all 6 phases, grid.sync() between dependent ones.
// ---------------------------------------------------------------------------
struct MegaParams {
    const int* eidx;
    unsigned int* tmp;
    int* cfill;
    int* colidx;
    int* rowp;
    const float* x;
    const float* W1; const float* att_s1; const float* att_d1; const float* bias1;
    const float* W2; const float* att_s2; const float* att_d2; const float* bias2;
    unsigned short* h1f16; unsigned short* hx16; unsigned short* h2f16;
    float* as1; float* ad1; float* as2; float* ad2;
    float* out;
    int E, etot, nb, nbA, nbG, N;
};

__global__ __launch_bounds__(1024, 4) void mega_kernel(MegaParams p)
{
    __shared__ __align__(16) char sm[SM_BYTES];
    cg::grid_group grid = cg::this_grid();
    const int GB = (int)gridDim.x;
    int t = threadIdx.x;

    // P0: zero coarse-bucket counters
    for (int i = (int)blockIdx.x * 1024 + t; i < NB_BUCKETS; i += GB * 1024)
        p.cfill[i] = 0;
    grid.sync();

    // P1: splitA (vb < nbA)  ||  gemm_attn layer 1 (vb >= nbA) — independent
    int tot1 = p.nbA + p.nbG;
    for (int vb = (int)blockIdx.x; vb < tot1; vb += GB) {
        __syncthreads();
        if (vb < p.nbA)
            splitA_body(sm, vb, p.eidx, p.tmp, p.cfill, p.E, p.etot, p.nb);
        else
            gemm_body<8, 4, false>(sm, vb - p.nbA, p.x, p.W1, p.att_s1, p.att_d1,
                                   p.h1f16, p.as1, p.ad1, p.N);
    }
    grid.sync();

    // P2: per-bucket counting sort -> col + rowp
    for (int vb = (int)blockIdx.x; vb < p.nb; vb += GB) {
        __syncthreads();
        passB_body(sm, vb, p.tmp, p.cfill, p.colidx, p.rowp, p.N, p.nb, p.etot);
    }
    grid.sync();

    // P3: layer-1 aggregate (16 nodes per virtual block)
    int nbagg = (p.N + 15) >> 4;
    for (int vb = (int)blockIdx.x; vb < nbagg; vb += GB)
        agg_body<4, 32, true, true>(sm, vb, p.rowp, p.colidx, p.h1f16,
                                    p.as1, p.ad1, p.bias1, p.hx16, p.N);
    grid.sync();

    // P4: layer-2 gemm+attn (reads fp16 hx)
    for (int vb = (int)blockIdx.x; vb < p.nbG; vb += GB) {
        __syncthreads();
        gemm_body<4, 1, true>(sm, vb, p.hx16, p.W2, p.att_s2, p.att_d2,
                              p.h2f16, p.as2, p.ad2, p.N);
    }
    grid.sync();

    // P5: layer-2 aggregate -> fp32 out
    for (int vb = (int)blockIdx.x; vb < nbagg; vb += GB)
        agg_body<1, 64, false, false>(sm, vb, p.rowp, p.colidx, p.h2f16,
                                      p.as2, p.ad2, p.bias2, p.out, p.N);
}

// ---------------------------------------------------------------------------
extern "C" void kernel_launch(void* const* d_in, const int* in_sizes, int n_in,
                              void* d_out, int out_size, void* d_ws, size_t ws_size,
                              hipStream_t stream)
{
    const float* x        = (const float*)d_in[0];
    const int*   eidx     = (const int*)  d_in[1];
    const float* W1       = (const float*)d_in[2];
    const float* att_src1 = (const float*)d_in[3];
    const float* att_dst1 = (const float*)d_in[4];
    const float* bias1    = (const float*)d_in[5];
    const float* W2       = (const float*)d_in[6];
    const float* att_src2 = (const float*)d_in[7];
    const float* att_dst2 = (const float*)d_in[8];
    const float* bias2    = (const float*)d_in[9];
    float* out = (float*)d_out;

    const int N_ = in_sizes[0] / 128;
    const int E_ = in_sizes[1] / 2;
    const int ET = E_ + N_;
    const int NB = (N_ + 255) / 256;

    char* p = (char*)d_ws;
    auto alloc = [&](size_t bytes) {
        void* r = (void*)p;
        p += ((bytes + 255) / 256) * 256;
        return r;
    };
    int* rowp  = (int*)alloc((size_t)(N_ + 1) * 4);
    int* cfill = (int*)alloc((size_t)NB_BUCKETS * 4);
    int* colidx = (int*)alloc((size_t)ET * 4);
    unsigned int*   tmp   = (unsigned int*)alloc((size_t)NB_BUCKETS * BCAP * 4);
    // h1f16 must not alias tmp: gemm1 runs concurrently with splitA
    unsigned short* h1f16 = (unsigned short*)alloc((size_t)N_ * 128 * 2);
    unsigned short* hx16  = (unsigned short*)alloc((size_t)N_ * 128 * 2);
    unsigned short* h2f16 = (unsigned short*)alloc((size_t)N_ * 64 * 2);
    float* as1 = (float*)alloc((size_t)N_ * 4 * 4);
    float* ad1 = (float*)alloc((size_t)N_ * 4 * 4);
    float* as2 = (float*)alloc((size_t)N_ * 4);
    float* ad2 = (float*)alloc((size_t)N_ * 4);
    (void)ws_size; (void)n_in; (void)out_size;

    MegaParams mp;
    mp.eidx = eidx; mp.tmp = tmp; mp.cfill = cfill;
    mp.colidx = colidx; mp.rowp = rowp;
    mp.x = x;
    mp.W1 = W1; mp.att_s1 = att_src1; mp.att_d1 = att_dst1; mp.bias1 = bias1;
    mp.W2 = W2; mp.att_s2 = att_src2; mp.att_d2 = att_dst2; mp.bias2 = bias2;
    mp.h1f16 = h1f16; mp.hx16 = hx16; mp.h2f16 = h2f16;
    mp.as1 = as1; mp.ad1 = ad1; mp.as2 = as2; mp.ad2 = ad2;
    mp.out = out;
    mp.E = E_; mp.etot = ET; mp.nb = NB;
    mp.nbA = (ET + 4095) / 4096;       // splitA virtual blocks (403)
    mp.nbG = (N_ + 255) / 256;         // gemm virtual blocks (196)
    mp.N = N_;

    void* kargs[] = { &mp };
    hipLaunchCooperativeKernel((const void*)mega_kernel,
                               dim3(256), dim3(1024), kargs, 0, stream);
}